// Round 15
// baseline (240.177 us; speedup 1.0000x reference)
//
#include <hip/hip_runtime.h>
#include <hip/hip_fp16.h>

// GCN 2-layer on MI355X — Round 25: R23 base (233us, best) with localC
// occupancy fix. R24's subtraction experiment exposed the real budget:
// countA+scans are only ~6us (int LDS hist atomics are bank-parallel;
// the 4.2cy/lane serialization applies to float-accumulate patterns) ->
// localC ~ 66us, the largest kernel, hidden below the top-5 cutoff.
// Cause: 86KB LDS -> 1 block/CU, 392 blocks, ~10 barriers each, no
// overlap. Fix: BC 4->8 (ranges ~8.2k edges, stage 36KB, total 46KB ->
// 3 blocks/CU, 784 blocks = fully resident). Downstream loops 8 buckets.
//
// g16[j] = half2(x[j]*dinv[j]).  layer1: hs16 via relu(dinv*(sum)+b1)@W2*dinv
// layer2: out[i] = dinv[i]*(sum hs16[src]+hs16[i]) + b2

#define EPB   8192   // edges per pass-A block
#define PART  2048   // nodes per partition
#define LPBIT 11
#define SRCB  18     // src bits in packed
#define BC    8      // localC sub-blocks per dp (was 4)
#define RSTR  2049   // runStart stride per (dp,b)
#define STCAP 9216   // localC LDS stage words (36 KB; mean range ~8.2k)
#define NSL1  256    // nodes per agg1 slice
#define CAP1  1280   // agg1 staged edges per bucket-phase (mean ~1020, +8σ)
#define NSL2  128    // nodes per agg2 slice
#define CAP2  768    // agg2 staged edges per bucket-phase (mean ~510, +11σ)

// ---------------- Pass A ----------------

__global__ __launch_bounds__(512) void countA_kernel(
    const int* __restrict__ dst, int* __restrict__ cntmat, int E, int P) {
    __shared__ int cnt[128];
    int tid = threadIdx.x;
    if (tid < 128) cnt[tid] = 0;
    __syncthreads();
    int nv4 = E >> 2;
    int b4 = (blockIdx.x * EPB) >> 2;
    int e4 = min(b4 + (EPB >> 2), nv4);
    const int4* d4 = (const int4*)dst;
    #pragma unroll
    for (int k = 0; k < (EPB >> 2); k += 512) {
        int i = b4 + k + tid;
        if (i < e4) {
            int4 d = d4[i];
            atomicAdd(&cnt[d.x >> LPBIT], 1);
            atomicAdd(&cnt[d.y >> LPBIT], 1);
            atomicAdd(&cnt[d.z >> LPBIT], 1);
            atomicAdd(&cnt[d.w >> LPBIT], 1);
        }
    }
    if (blockIdx.x == gridDim.x - 1) {  // scalar tail (E % 4)
        int e = (nv4 << 2) + tid;
        if (e < E) atomicAdd(&cnt[dst[e] >> LPBIT], 1);
    }
    __syncthreads();
    int* row = cntmat + (size_t)blockIdx.x * P;
    if (tid < P) row[tid] = cnt[tid];
}

__global__ __launch_bounds__(256) void colscanA_kernel(
    int* __restrict__ cntmat, int* __restrict__ colTotal, int B, int P) {
    __shared__ int sdata[256];
    int p = blockIdx.x, tid = threadIdx.x;
    int v[4];
    int s = 0;
    #pragma unroll
    for (int k = 0; k < 4; k++) {
        int b = tid * 4 + k;
        v[k] = (b < B) ? cntmat[(size_t)b * P + p] : 0;
        s += v[k];
    }
    int x = s;
    sdata[tid] = x;
    __syncthreads();
    for (int off = 1; off < 256; off <<= 1) {
        int t = (tid >= off) ? sdata[tid - off] : 0;
        __syncthreads();
        x += t;
        sdata[tid] = x;
        __syncthreads();
    }
    int run = x - s;
    #pragma unroll
    for (int k = 0; k < 4; k++) {
        int b = tid * 4 + k;
        if (b < B) cntmat[(size_t)b * P + p] = run;
        run += v[k];
    }
    if (tid == 255) colTotal[p] = x;
}

__global__ __launch_bounds__(256) void totalscanA_kernel(
    const int* __restrict__ colTotal, int* __restrict__ colStart,
    int P, int E) {
    __shared__ int sdata[256];
    int tid = threadIdx.x;
    int v[4];
    int s = 0;
    #pragma unroll
    for (int k = 0; k < 4; k++) {
        int i = tid * 4 + k;
        v[k] = (i < P) ? colTotal[i] : 0;
        s += v[k];
    }
    int x = s;
    sdata[tid] = x;
    __syncthreads();
    for (int off = 1; off < 256; off <<= 1) {
        int t = (tid >= off) ? sdata[tid - off] : 0;
        __syncthreads();
        x += t;
        sdata[tid] = x;
        __syncthreads();
    }
    int run = x - s;
    #pragma unroll
    for (int k = 0; k < 4; k++) {
        int i = tid * 4 + k;
        if (i < P) colStart[i] = run;
        run += v[k];
    }
    if (tid == 0) colStart[P] = E;
}

__global__ __launch_bounds__(512) void scatterA_kernel(
    const int* __restrict__ src, const int* __restrict__ dst,
    const int* __restrict__ cntmat, const int* __restrict__ colStart,
    unsigned* __restrict__ packed, int E, int P) {
    __shared__ int cur[128];
    int tid = threadIdx.x;
    if (tid < P) cur[tid] = colStart[tid] + cntmat[(size_t)blockIdx.x * P + tid];
    __syncthreads();
    int nv4 = E >> 2;
    int b4 = (blockIdx.x * EPB) >> 2;
    int e4 = min(b4 + (EPB >> 2), nv4);
    const int4* d4 = (const int4*)dst;
    const int4* s4 = (const int4*)src;
    #pragma unroll
    for (int k = 0; k < (EPB >> 2); k += 512) {
        int i = b4 + k + tid;
        if (i < e4) {
            int4 d = d4[i];
            int4 sv = s4[i];
            int p0 = atomicAdd(&cur[d.x >> LPBIT], 1);
            packed[p0] = ((unsigned)(d.x & (PART - 1)) << SRCB) | (unsigned)sv.x;
            int p1 = atomicAdd(&cur[d.y >> LPBIT], 1);
            packed[p1] = ((unsigned)(d.y & (PART - 1)) << SRCB) | (unsigned)sv.y;
            int p2 = atomicAdd(&cur[d.z >> LPBIT], 1);
            packed[p2] = ((unsigned)(d.z & (PART - 1)) << SRCB) | (unsigned)sv.z;
            int p3 = atomicAdd(&cur[d.w >> LPBIT], 1);
            packed[p3] = ((unsigned)(d.w & (PART - 1)) << SRCB) | (unsigned)sv.w;
        }
    }
    if (blockIdx.x == gridDim.x - 1) {  // scalar tail
        int e = (nv4 << 2) + tid;
        if (e < E) {
            int d = dst[e];
            int pos = atomicAdd(&cur[d >> LPBIT], 1);
            packed[pos] = ((unsigned)(d & (PART - 1)) << SRCB) | (unsigned)src[e];
        }
    }
}

// ---------------- localC: in-place LDS counting sort per ~8.2k range -----

__global__ __launch_bounds__(512) void localC_kernel(
    const unsigned* __restrict__ packed, const int* __restrict__ colStart,
    int* __restrict__ runStart, int* __restrict__ srcsorted) {
    __shared__ int hist[PART];      // counts -> absolute cursors
    __shared__ int sdata[512];
    __shared__ unsigned stage[STCAP];
    int tid = threadIdx.x;
    int dp = blockIdx.x >> 3, b = blockIdx.x & (BC - 1);
    int s0 = colStart[dp], len = colStart[dp + 1] - s0;
    int lo = s0 + (int)(((long long)len * b) / BC);
    int hi = s0 + (int)(((long long)len * (b + 1)) / BC);
    for (int k = tid; k < PART; k += 512) hist[k] = 0;
    __syncthreads();
    for (int i = lo + tid; i < hi; i += 512)
        atomicAdd(&hist[packed[i] >> SRCB], 1);
    __syncthreads();
    // exclusive scan of hist[2048], 4 elems/thread
    int off = tid * 4;
    int v0 = hist[off], v1 = hist[off + 1], v2 = hist[off + 2], v3 = hist[off + 3];
    int s = v0 + v1 + v2 + v3;
    int x = s;
    sdata[tid] = x;
    __syncthreads();
    for (int o = 1; o < 512; o <<= 1) {
        int t = (tid >= o) ? sdata[tid - o] : 0;
        __syncthreads();
        x += t;
        sdata[tid] = x;
        __syncthreads();
    }
    int run = x - s;  // exclusive prefix of this thread's 4 buckets
    int* rs = runStart + (size_t)(dp * BC + b) * RSTR;
    int c0 = lo + run, c1 = c0 + v0, c2 = c1 + v1, c3 = c2 + v2;
    rs[off] = c0; rs[off + 1] = c1; rs[off + 2] = c2; rs[off + 3] = c3;
    __syncthreads();  // all v-reads done before cursor overwrite
    hist[off] = c0; hist[off + 1] = c1; hist[off + 2] = c2; hist[off + 3] = c3;
    if (tid == 0) rs[PART] = hi;  // end sentinel
    __syncthreads();
    // place into LDS stage (absolute pos - lo), then coalesced flush
    int total = hi - lo;
    bool ovf = total > STCAP;
    for (int i = lo + tid; i < hi; i += 512) {
        unsigned w = packed[i];
        int pos = atomicAdd(&hist[w >> SRCB], 1);
        unsigned sv = w & ((1u << SRCB) - 1);
        if (!ovf) stage[pos - lo] = sv;
        else srcsorted[pos] = (int)sv;
    }
    __syncthreads();
    if (!ovf)
        for (int j = tid; j < total; j += 512) srcsorted[lo + j] = (int)stage[j];
}

// ---------------- Node-side ----------------

__global__ __launch_bounds__(512) void dinvg_kernel(
    const int* __restrict__ runStart, const float* __restrict__ x,
    float* __restrict__ dinv, unsigned* __restrict__ g16, int n) {
    int i = blockIdx.x * 512 + threadIdx.x;
    if (i >= n) return;
    int dp = i >> LPBIT, ld = i & (PART - 1);
    int deg = 0;
    #pragma unroll
    for (int b = 0; b < BC; b++) {
        const int* rs = runStart + (size_t)(dp * BC + b) * RSTR + ld;
        deg += rs[1] - rs[0];
    }
    float d = rsqrtf((float)deg + 1.0f);  // +1 self-loop
    dinv[i] = d;
    float2 xv = ((const float2*)x)[i];
    __half2 h = __floats2half2_rn(xv.x * d, xv.y * d);
    g16[i] = *(unsigned*)&h;
}

__device__ __forceinline__ float h2_comp(unsigned w, int c) {
    __half2 h = *(__half2*)&w;
    return __half2float(c ? __high2half(h) : __low2half(h));
}

// ---------------- Fused slice aggregation (fp16 payloads, 8 buckets) -----

__global__ __launch_bounds__(512) void agg1x_kernel(
    const int* __restrict__ srcsorted, const int* __restrict__ runStart,
    const unsigned* __restrict__ g16, const float* __restrict__ dinv,
    const float* __restrict__ W1, const float* __restrict__ b1,
    const float* __restrict__ W2, unsigned* __restrict__ hs16, int n) {
    __shared__ unsigned stage[CAP1];
    __shared__ int srs[NSL1 + 1];
    __shared__ float sres[NSL1][2];
    int tid = threadIdx.x;
    int dp = blockIdx.x >> 3, sl = blockIdx.x & 7;
    int nid = tid >> 1, c = tid & 1;       // 256 nodes x 2 comps
    float acc = 0.0f;
    #pragma unroll
    for (int b = 0; b < BC; b++) {
        const int* rs = runStart + (size_t)(dp * BC + b) * RSTR + sl * NSL1;
        if (tid <= NSL1) srs[tid] = rs[tid];
        __syncthreads();
        int lo = srs[0], hi = srs[NSL1];
        bool ovf = (hi - lo) > CAP1;       // expected never (+8σ)
        if (!ovf)
            for (int e = lo + tid; e < hi; e += 512)
                stage[e - lo] = g16[srcsorted[e]];   // 1 dword gather
        __syncthreads();
        int a = srs[nid] - lo, bnd = srs[nid + 1] - lo;
        if (!ovf) {
            for (int j = a; j < bnd; j++) acc += h2_comp(stage[j], c);
        } else {
            for (int j = a; j < bnd; j++)
                acc += h2_comp(g16[srcsorted[lo + j]], c);
        }
        __syncthreads();                   // stage reuse next bucket
    }
    sres[nid][c] = acc;
    __syncthreads();
    if (tid < NSL1) {
        int i = ((dp << LPBIT) | (sl * NSL1)) + tid;
        if (i < n) {
            float d = dinv[i];
            unsigned gw = g16[i];
            float s0 = (sres[tid][0] + h2_comp(gw, 0)) * d;
            float s1 = (sres[tid][1] + h2_comp(gw, 1)) * d;
            float oc0 = 0.0f, oc1 = 0.0f, oc2 = 0.0f, oc3 = 0.0f;
            #pragma unroll
            for (int f = 0; f < 8; f++) {
                float h = fmaxf(s0 * W1[f] + s1 * W1[8 + f] + b1[f], 0.0f);
                oc0 += h * W2[4 * f];
                oc1 += h * W2[4 * f + 1];
                oc2 += h * W2[4 * f + 2];
                oc3 += h * W2[4 * f + 3];
            }
            __half2 h01 = __floats2half2_rn(oc0 * d, oc1 * d);
            __half2 h23 = __floats2half2_rn(oc2 * d, oc3 * d);
            uint2 o;
            o.x = *(unsigned*)&h01;
            o.y = *(unsigned*)&h23;
            ((uint2*)hs16)[i] = o;
        }
    }
}

__global__ __launch_bounds__(512) void agg2x_kernel(
    const int* __restrict__ srcsorted, const int* __restrict__ runStart,
    const unsigned* __restrict__ hs16, const float* __restrict__ dinv,
    const float* __restrict__ b2, float* __restrict__ out, int n) {
    __shared__ uint2 stage[CAP2];
    __shared__ int srs[NSL2 + 1];
    int tid = threadIdx.x;
    int dp = blockIdx.x >> 4, sl = blockIdx.x & 15;
    int nid = tid >> 2, c = tid & 3;       // 128 nodes x 4 comps
    const uint2* hp = (const uint2*)hs16;
    float acc = 0.0f;
    #pragma unroll
    for (int b = 0; b < BC; b++) {
        const int* rs = runStart + (size_t)(dp * BC + b) * RSTR + sl * NSL2;
        if (tid <= NSL2) srs[tid] = rs[tid];
        __syncthreads();
        int lo = srs[0], hi = srs[NSL2];
        bool ovf = (hi - lo) > CAP2;       // expected never (+11σ)
        if (!ovf)
            for (int e = lo + tid; e < hi; e += 512)
                stage[e - lo] = hp[srcsorted[e]];    // 2 dword gather
        __syncthreads();
        int a = srs[nid] - lo, bnd = srs[nid + 1] - lo;
        if (!ovf) {
            const unsigned* st = (const unsigned*)stage;
            for (int j = a; j < bnd; j++)
                acc += h2_comp(st[j * 2 + (c >> 1)], c & 1);
        } else {
            for (int j = a; j < bnd; j++) {
                uint2 w = hp[srcsorted[lo + j]];
                acc += h2_comp((c >> 1) ? w.y : w.x, c & 1);
            }
        }
        __syncthreads();                   // stage reuse next bucket
    }
    int i = ((dp << LPBIT) | (sl * NSL2)) + nid;
    if (i < n) {
        float d = dinv[i];
        uint2 hw = hp[i];
        float hv = h2_comp((c >> 1) ? hw.y : hw.x, c & 1);
        out[4 * (size_t)i + c] = d * (acc + hv) + b2[c];  // coalesced
    }
}

extern "C" void kernel_launch(void* const* d_in, const int* in_sizes, int n_in,
                              void* d_out, int out_size, void* d_ws, size_t ws_size,
                              hipStream_t stream) {
    const float* x   = (const float*)d_in[0];
    const int*   ei  = (const int*)d_in[1];
    const float* W1  = (const float*)d_in[2];
    const float* b1  = (const float*)d_in[3];
    const float* W2  = (const float*)d_in[4];
    const float* b2  = (const float*)d_in[5];
    float* out = (float*)d_out;

    const int n = in_sizes[0] / 2;  // x is [N,2]
    const int E = in_sizes[1] / 2;  // edge_index is [2,E]
    const int* src = ei;
    const int* dst = ei + E;

    const int P  = (n + PART - 1) >> LPBIT;  // 98
    const int B1 = (E + EPB - 1) / EPB;      // 782

    int* ws = (int*)d_ws;
    int* colTotal = ws;                                      // 1024
    int* colStart = ws + 1024;                               // 1024
    int* cntmatA  = ws + 2048;                               // B1*P
    size_t cmsz = (((size_t)B1 * P) + 3) & ~(size_t)3;
    int* runStart = cntmatA + cmsz;                          // P*BC*RSTR
    size_t rssz = (((size_t)P * BC * RSTR) + 3) & ~(size_t)3;
    unsigned* packed = (unsigned*)(runStart + rssz);         // E
    int* srcsorted = (int*)(packed + E);                     // E
    // packed region dead after localC; overlay node buffers (4*nd <= E):
    size_t nd = (size_t)P << LPBIT;                          // 200704
    float*    dinv = (float*)packed;                         // nd
    unsigned* g16  = (unsigned*)(dinv + nd);                 // nd (half2)
    unsigned* hs16 = g16 + nd;                               // 2*nd (2xhalf2)

    const int gN  = (n + 511) / 512;
    const int gA1 = P * (PART / NSL1);   // 784
    const int gA2 = P * (PART / NSL2);   // 1568

    countA_kernel    <<<B1, 512, 0, stream>>>(dst, cntmatA, E, P);
    colscanA_kernel  <<<P, 256, 0, stream>>>(cntmatA, colTotal, B1, P);
    totalscanA_kernel<<<1, 256, 0, stream>>>(colTotal, colStart, P, E);
    scatterA_kernel  <<<B1, 512, 0, stream>>>(src, dst, cntmatA, colStart, packed, E, P);
    localC_kernel    <<<P * BC, 512, 0, stream>>>(packed, colStart, runStart, srcsorted);
    dinvg_kernel     <<<gN, 512, 0, stream>>>(runStart, x, dinv, g16, n);
    agg1x_kernel     <<<gA1, 512, 0, stream>>>(srcsorted, runStart, g16, dinv, W1, b1, W2, hs16, n);
    agg2x_kernel     <<<gA2, 512, 0, stream>>>(srcsorted, runStart, hs16, dinv, b2, out, n);
}

// Round 16
// 232.295 us; speedup vs baseline: 1.0339x; 1.0339x over previous
//
#include <hip/hip_runtime.h>
#include <hip/hip_fp16.h>

// GCN 2-layer on MI355X — Round 26: pure revert to R23 (233.2us, session
// best). R24 (merged front-end) and R25 (localC BC=8) both regressed;
// four consecutive structural theories falsified. Measured constants:
//  - returning LDS atomics ~4.2cy/lane -> each counting-sort placement
//    pass (scatterA, localC) ~44-55us; int no-return atomics ~free.
//  - float LDS atomics pay the tax per component (histogram agg: 174us).
//  - scattered 4B global stores dirty full 64B lines (direct CSR: 627us).
//  - random-gather agg ~42us regardless of structure or payload width.
//  - harness ws-poison fill: 44us, fixed.
// Accounted floor ~230us; this kernel measures 233 (+/-3) — structural.
//
// Pipeline: countA -> colscan -> totalscan -> scatterA (partition sort)
// -> localC (node sort, runStart CSR) -> dinvg -> agg1x -> agg2x
// with fp16 payloads (g16 half2, hs16 2xhalf2).
//
// g16[j] = half2(x[j]*dinv[j]).  layer1: hs16 via relu(dinv*(sum)+b1)@W2*dinv
// layer2: out[i] = dinv[i]*(sum hs16[src]+hs16[i]) + b2

#define EPB   8192   // edges per pass-A block
#define PART  2048   // nodes per partition
#define LPBIT 11
#define SRCB  18     // src bits in packed
#define BC    4      // localC sub-blocks per dp
#define RSTR  2049   // runStart stride per (dp,b)
#define STCAP 17408  // LDS stage words (68 KB); max expected ~16.6k
#define NSL1  256    // nodes per agg1 slice (8 slices per dp)
#define CAP1  2304   // agg1 staged edges per bucket-phase (mean ~2064, +5σ)
#define NSL2  128    // nodes per agg2 slice (16 slices per dp)
#define CAP2  1280   // agg2 staged edges per bucket-phase (mean ~1032, +7σ)

// ---------------- Pass A ----------------

__global__ __launch_bounds__(512) void countA_kernel(
    const int* __restrict__ dst, int* __restrict__ cntmat, int E, int P) {
    __shared__ int cnt[128];
    int tid = threadIdx.x;
    if (tid < 128) cnt[tid] = 0;
    __syncthreads();
    int nv4 = E >> 2;
    int b4 = (blockIdx.x * EPB) >> 2;
    int e4 = min(b4 + (EPB >> 2), nv4);
    const int4* d4 = (const int4*)dst;
    #pragma unroll
    for (int k = 0; k < (EPB >> 2); k += 512) {
        int i = b4 + k + tid;
        if (i < e4) {
            int4 d = d4[i];
            atomicAdd(&cnt[d.x >> LPBIT], 1);
            atomicAdd(&cnt[d.y >> LPBIT], 1);
            atomicAdd(&cnt[d.z >> LPBIT], 1);
            atomicAdd(&cnt[d.w >> LPBIT], 1);
        }
    }
    if (blockIdx.x == gridDim.x - 1) {  // scalar tail (E % 4)
        int e = (nv4 << 2) + tid;
        if (e < E) atomicAdd(&cnt[dst[e] >> LPBIT], 1);
    }
    __syncthreads();
    int* row = cntmat + (size_t)blockIdx.x * P;
    if (tid < P) row[tid] = cnt[tid];
}

__global__ __launch_bounds__(256) void colscanA_kernel(
    int* __restrict__ cntmat, int* __restrict__ colTotal, int B, int P) {
    __shared__ int sdata[256];
    int p = blockIdx.x, tid = threadIdx.x;
    int v[4];
    int s = 0;
    #pragma unroll
    for (int k = 0; k < 4; k++) {
        int b = tid * 4 + k;
        v[k] = (b < B) ? cntmat[(size_t)b * P + p] : 0;
        s += v[k];
    }
    int x = s;
    sdata[tid] = x;
    __syncthreads();
    for (int off = 1; off < 256; off <<= 1) {
        int t = (tid >= off) ? sdata[tid - off] : 0;
        __syncthreads();
        x += t;
        sdata[tid] = x;
        __syncthreads();
    }
    int run = x - s;
    #pragma unroll
    for (int k = 0; k < 4; k++) {
        int b = tid * 4 + k;
        if (b < B) cntmat[(size_t)b * P + p] = run;
        run += v[k];
    }
    if (tid == 255) colTotal[p] = x;
}

__global__ __launch_bounds__(256) void totalscanA_kernel(
    const int* __restrict__ colTotal, int* __restrict__ colStart,
    int P, int E) {
    __shared__ int sdata[256];
    int tid = threadIdx.x;
    int v[4];
    int s = 0;
    #pragma unroll
    for (int k = 0; k < 4; k++) {
        int i = tid * 4 + k;
        v[k] = (i < P) ? colTotal[i] : 0;
        s += v[k];
    }
    int x = s;
    sdata[tid] = x;
    __syncthreads();
    for (int off = 1; off < 256; off <<= 1) {
        int t = (tid >= off) ? sdata[tid - off] : 0;
        __syncthreads();
        x += t;
        sdata[tid] = x;
        __syncthreads();
    }
    int run = x - s;
    #pragma unroll
    for (int k = 0; k < 4; k++) {
        int i = tid * 4 + k;
        if (i < P) colStart[i] = run;
        run += v[k];
    }
    if (tid == 0) colStart[P] = E;
}

__global__ __launch_bounds__(512) void scatterA_kernel(
    const int* __restrict__ src, const int* __restrict__ dst,
    const int* __restrict__ cntmat, const int* __restrict__ colStart,
    unsigned* __restrict__ packed, int E, int P) {
    __shared__ int cur[128];
    int tid = threadIdx.x;
    if (tid < P) cur[tid] = colStart[tid] + cntmat[(size_t)blockIdx.x * P + tid];
    __syncthreads();
    int nv4 = E >> 2;
    int b4 = (blockIdx.x * EPB) >> 2;
    int e4 = min(b4 + (EPB >> 2), nv4);
    const int4* d4 = (const int4*)dst;
    const int4* s4 = (const int4*)src;
    #pragma unroll
    for (int k = 0; k < (EPB >> 2); k += 512) {
        int i = b4 + k + tid;
        if (i < e4) {
            int4 d = d4[i];
            int4 sv = s4[i];
            int p0 = atomicAdd(&cur[d.x >> LPBIT], 1);
            packed[p0] = ((unsigned)(d.x & (PART - 1)) << SRCB) | (unsigned)sv.x;
            int p1 = atomicAdd(&cur[d.y >> LPBIT], 1);
            packed[p1] = ((unsigned)(d.y & (PART - 1)) << SRCB) | (unsigned)sv.y;
            int p2 = atomicAdd(&cur[d.z >> LPBIT], 1);
            packed[p2] = ((unsigned)(d.z & (PART - 1)) << SRCB) | (unsigned)sv.z;
            int p3 = atomicAdd(&cur[d.w >> LPBIT], 1);
            packed[p3] = ((unsigned)(d.w & (PART - 1)) << SRCB) | (unsigned)sv.w;
        }
    }
    if (blockIdx.x == gridDim.x - 1) {  // scalar tail
        int e = (nv4 << 2) + tid;
        if (e < E) {
            int d = dst[e];
            int pos = atomicAdd(&cur[d >> LPBIT], 1);
            packed[pos] = ((unsigned)(d & (PART - 1)) << SRCB) | (unsigned)src[e];
        }
    }
}

// ---------------- localC: in-place LDS counting sort per 16k range --------

__global__ __launch_bounds__(512) void localC_kernel(
    const unsigned* __restrict__ packed, const int* __restrict__ colStart,
    int* __restrict__ runStart, int* __restrict__ srcsorted) {
    __shared__ int hist[PART];      // counts -> absolute cursors
    __shared__ int sdata[512];
    __shared__ unsigned stage[STCAP];
    int tid = threadIdx.x;
    int dp = blockIdx.x >> 2, b = blockIdx.x & (BC - 1);
    int s0 = colStart[dp], len = colStart[dp + 1] - s0;
    int lo = s0 + (int)(((long long)len * b) / BC);
    int hi = s0 + (int)(((long long)len * (b + 1)) / BC);
    for (int k = tid; k < PART; k += 512) hist[k] = 0;
    __syncthreads();
    for (int i = lo + tid; i < hi; i += 512)
        atomicAdd(&hist[packed[i] >> SRCB], 1);
    __syncthreads();
    // exclusive scan of hist[2048], 4 elems/thread
    int off = tid * 4;
    int v0 = hist[off], v1 = hist[off + 1], v2 = hist[off + 2], v3 = hist[off + 3];
    int s = v0 + v1 + v2 + v3;
    int x = s;
    sdata[tid] = x;
    __syncthreads();
    for (int o = 1; o < 512; o <<= 1) {
        int t = (tid >= o) ? sdata[tid - o] : 0;
        __syncthreads();
        x += t;
        sdata[tid] = x;
        __syncthreads();
    }
    int run = x - s;  // exclusive prefix of this thread's 4 buckets
    int* rs = runStart + (size_t)(dp * BC + b) * RSTR;
    int c0 = lo + run, c1 = c0 + v0, c2 = c1 + v1, c3 = c2 + v2;
    rs[off] = c0; rs[off + 1] = c1; rs[off + 2] = c2; rs[off + 3] = c3;
    __syncthreads();  // all v-reads done before cursor overwrite
    hist[off] = c0; hist[off + 1] = c1; hist[off + 2] = c2; hist[off + 3] = c3;
    if (tid == 0) rs[PART] = hi;  // end sentinel
    __syncthreads();
    // place into LDS stage (absolute pos - lo), then coalesced flush
    int total = hi - lo;
    bool ovf = total > STCAP;
    for (int i = lo + tid; i < hi; i += 512) {
        unsigned w = packed[i];
        int pos = atomicAdd(&hist[w >> SRCB], 1);
        unsigned sv = w & ((1u << SRCB) - 1);
        if (!ovf) stage[pos - lo] = sv;
        else srcsorted[pos] = (int)sv;
    }
    __syncthreads();
    if (!ovf)
        for (int j = tid; j < total; j += 512) srcsorted[lo + j] = (int)stage[j];
}

// ---------------- Node-side ----------------

__global__ __launch_bounds__(512) void dinvg_kernel(
    const int* __restrict__ runStart, const float* __restrict__ x,
    float* __restrict__ dinv, unsigned* __restrict__ g16, int n) {
    int i = blockIdx.x * 512 + threadIdx.x;
    if (i >= n) return;
    int dp = i >> LPBIT, ld = i & (PART - 1);
    int deg = 0;
    #pragma unroll
    for (int b = 0; b < BC; b++) {
        const int* rs = runStart + (size_t)(dp * BC + b) * RSTR + ld;
        deg += rs[1] - rs[0];
    }
    float d = rsqrtf((float)deg + 1.0f);  // +1 self-loop
    dinv[i] = d;
    float2 xv = ((const float2*)x)[i];
    __half2 h = __floats2half2_rn(xv.x * d, xv.y * d);
    g16[i] = *(unsigned*)&h;
}

__device__ __forceinline__ float h2_comp(unsigned w, int c) {
    __half2 h = *(__half2*)&w;
    return __half2float(c ? __high2half(h) : __low2half(h));
}

// ---------------- Fused slice aggregation (fp16 payloads) ----------------

__global__ __launch_bounds__(512) void agg1x_kernel(
    const int* __restrict__ srcsorted, const int* __restrict__ runStart,
    const unsigned* __restrict__ g16, const float* __restrict__ dinv,
    const float* __restrict__ W1, const float* __restrict__ b1,
    const float* __restrict__ W2, unsigned* __restrict__ hs16, int n) {
    __shared__ unsigned stage[CAP1];
    __shared__ int srs[NSL1 + 1];
    __shared__ float sres[NSL1][2];
    int tid = threadIdx.x;
    int dp = blockIdx.x >> 3, sl = blockIdx.x & 7;
    int nid = tid >> 1, c = tid & 1;       // 256 nodes x 2 comps
    float acc = 0.0f;
    #pragma unroll
    for (int b = 0; b < BC; b++) {
        const int* rs = runStart + (size_t)(dp * BC + b) * RSTR + sl * NSL1;
        if (tid <= NSL1) srs[tid] = rs[tid];
        __syncthreads();
        int lo = srs[0], hi = srs[NSL1];
        bool ovf = (hi - lo) > CAP1;       // expected never (+5σ)
        if (!ovf)
            for (int e = lo + tid; e < hi; e += 512)
                stage[e - lo] = g16[srcsorted[e]];   // 1 dword gather
        __syncthreads();
        int a = srs[nid] - lo, bnd = srs[nid + 1] - lo;
        if (!ovf) {
            for (int j = a; j < bnd; j++) acc += h2_comp(stage[j], c);
        } else {
            for (int j = a; j < bnd; j++)
                acc += h2_comp(g16[srcsorted[lo + j]], c);
        }
        __syncthreads();                   // stage reuse next bucket
    }
    sres[nid][c] = acc;
    __syncthreads();
    if (tid < NSL1) {
        int i = ((dp << LPBIT) | (sl * NSL1)) + tid;
        if (i < n) {
            float d = dinv[i];
            unsigned gw = g16[i];
            float s0 = (sres[tid][0] + h2_comp(gw, 0)) * d;
            float s1 = (sres[tid][1] + h2_comp(gw, 1)) * d;
            float oc0 = 0.0f, oc1 = 0.0f, oc2 = 0.0f, oc3 = 0.0f;
            #pragma unroll
            for (int f = 0; f < 8; f++) {
                float h = fmaxf(s0 * W1[f] + s1 * W1[8 + f] + b1[f], 0.0f);
                oc0 += h * W2[4 * f];
                oc1 += h * W2[4 * f + 1];
                oc2 += h * W2[4 * f + 2];
                oc3 += h * W2[4 * f + 3];
            }
            __half2 h01 = __floats2half2_rn(oc0 * d, oc1 * d);
            __half2 h23 = __floats2half2_rn(oc2 * d, oc3 * d);
            uint2 o;
            o.x = *(unsigned*)&h01;
            o.y = *(unsigned*)&h23;
            ((uint2*)hs16)[i] = o;
        }
    }
}

__global__ __launch_bounds__(512) void agg2x_kernel(
    const int* __restrict__ srcsorted, const int* __restrict__ runStart,
    const unsigned* __restrict__ hs16, const float* __restrict__ dinv,
    const float* __restrict__ b2, float* __restrict__ out, int n) {
    __shared__ uint2 stage[CAP2];
    __shared__ int srs[NSL2 + 1];
    int tid = threadIdx.x;
    int dp = blockIdx.x >> 4, sl = blockIdx.x & 15;
    int nid = tid >> 2, c = tid & 3;       // 128 nodes x 4 comps
    const uint2* hp = (const uint2*)hs16;
    float acc = 0.0f;
    #pragma unroll
    for (int b = 0; b < BC; b++) {
        const int* rs = runStart + (size_t)(dp * BC + b) * RSTR + sl * NSL2;
        if (tid <= NSL2) srs[tid] = rs[tid];
        __syncthreads();
        int lo = srs[0], hi = srs[NSL2];
        bool ovf = (hi - lo) > CAP2;       // expected never (+7σ)
        if (!ovf)
            for (int e = lo + tid; e < hi; e += 512)
                stage[e - lo] = hp[srcsorted[e]];    // 2 dword gather
        __syncthreads();
        int a = srs[nid] - lo, bnd = srs[nid + 1] - lo;
        if (!ovf) {
            const unsigned* st = (const unsigned*)stage;
            for (int j = a; j < bnd; j++)
                acc += h2_comp(st[j * 2 + (c >> 1)], c & 1);
        } else {
            for (int j = a; j < bnd; j++) {
                uint2 w = hp[srcsorted[lo + j]];
                acc += h2_comp((c >> 1) ? w.y : w.x, c & 1);
            }
        }
        __syncthreads();                   // stage reuse next bucket
    }
    int i = ((dp << LPBIT) | (sl * NSL2)) + nid;
    if (i < n) {
        float d = dinv[i];
        uint2 hw = hp[i];
        float hv = h2_comp((c >> 1) ? hw.y : hw.x, c & 1);
        out[4 * (size_t)i + c] = d * (acc + hv) + b2[c];  // coalesced
    }
}

extern "C" void kernel_launch(void* const* d_in, const int* in_sizes, int n_in,
                              void* d_out, int out_size, void* d_ws, size_t ws_size,
                              hipStream_t stream) {
    const float* x   = (const float*)d_in[0];
    const int*   ei  = (const int*)d_in[1];
    const float* W1  = (const float*)d_in[2];
    const float* b1  = (const float*)d_in[3];
    const float* W2  = (const float*)d_in[4];
    const float* b2  = (const float*)d_in[5];
    float* out = (float*)d_out;

    const int n = in_sizes[0] / 2;  // x is [N,2]
    const int E = in_sizes[1] / 2;  // edge_index is [2,E]
    const int* src = ei;
    const int* dst = ei + E;

    const int P  = (n + PART - 1) >> LPBIT;  // 98
    const int B1 = (E + EPB - 1) / EPB;      // 782

    int* ws = (int*)d_ws;
    int* colTotal = ws;                                      // 1024
    int* colStart = ws + 1024;                               // 1024
    int* cntmatA  = ws + 2048;                               // B1*P
    size_t cmsz = (((size_t)B1 * P) + 3) & ~(size_t)3;
    int* runStart = cntmatA + cmsz;                          // P*BC*RSTR
    size_t rssz = (((size_t)P * BC * RSTR) + 3) & ~(size_t)3;
    unsigned* packed = (unsigned*)(runStart + rssz);         // E
    int* srcsorted = (int*)(packed + E);                     // E
    // packed region dead after localC; overlay node buffers (4*nd <= E):
    size_t nd = (size_t)P << LPBIT;                          // 200704
    float*    dinv = (float*)packed;                         // nd
    unsigned* g16  = (unsigned*)(dinv + nd);                 // nd (half2)
    unsigned* hs16 = g16 + nd;                               // 2*nd (2xhalf2)

    const int gN  = (n + 511) / 512;
    const int gA1 = P * (PART / NSL1);   // 784
    const int gA2 = P * (PART / NSL2);   // 1568

    countA_kernel    <<<B1, 512, 0, stream>>>(dst, cntmatA, E, P);
    colscanA_kernel  <<<P, 256, 0, stream>>>(cntmatA, colTotal, B1, P);
    totalscanA_kernel<<<1, 256, 0, stream>>>(colTotal, colStart, P, E);
    scatterA_kernel  <<<B1, 512, 0, stream>>>(src, dst, cntmatA, colStart, packed, E, P);
    localC_kernel    <<<P * BC, 512, 0, stream>>>(packed, colStart, runStart, srcsorted);
    dinvg_kernel     <<<gN, 512, 0, stream>>>(runStart, x, dinv, g16, n);
    agg1x_kernel     <<<gA1, 512, 0, stream>>>(srcsorted, runStart, g16, dinv, W1, b1, W2, hs16, n);
    agg2x_kernel     <<<gA2, 512, 0, stream>>>(srcsorted, runStart, hs16, dinv, b2, out, n);
}